// Round 1
// baseline (732.820 us; speedup 1.0000x reference)
//
#include <hip/hip_runtime.h>
#include <math.h>

// Problem dims (fixed)
#define BB    32
#define TENC  1024
#define TDEC  512
#define DDIM  512
#define NST   512

#define TILE_M 64
#define TILE_N 64
#define TILE_K 16

// C[M,N] = A[M,K] @ op(B) (+bias). A row-major lda=K.
// B_TRANS=true : B stored [N][K] (row-contiguous along reduction), ldb = K-stride
// B_TRANS=false: B stored [K][N], ldb = N-stride
template<bool B_TRANS, bool ADD_BIAS>
__global__ __launch_bounds__(256)
void gemm_f32(const float* __restrict__ A, const float* __restrict__ Bm,
              const float* __restrict__ bias, float* __restrict__ C,
              int M, int N, int K, int lda, int ldb,
              long strideA, long strideB, long strideC)
{
    __shared__ float As[TILE_K][TILE_M + 4];
    __shared__ float Bs[TILE_K][TILE_N + 4];

    const int b = blockIdx.z;
    A  += (long)b * strideA;
    Bm += (long)b * strideB;
    C  += (long)b * strideC;

    const int tid = threadIdx.x;
    const int tx = tid & 15;   // 0..15 -> output cols (x4)
    const int ty = tid >> 4;   // 0..15 -> output rows (x4)

    const int row0 = blockIdx.y * TILE_M;
    const int col0 = blockIdx.x * TILE_N;

    // loader indices (64x16 tile, transposed store)
    const int am = tid >> 2;          // 0..63
    const int ak = (tid & 3) * 4;     // 0,4,8,12

    float acc[4][4] = {};

    for (int kt = 0; kt < K; kt += TILE_K) {
        float4 a4 = *(const float4*)&A[(long)(row0 + am) * lda + kt + ak];
        float4 b4;
        if (B_TRANS) {
            b4 = *(const float4*)&Bm[(long)(col0 + am) * ldb + kt + ak];
        } else {
            const int bk_ = tid >> 4;        // 0..15
            const int bn  = (tid & 15) * 4;  // 0..60
            b4 = *(const float4*)&Bm[(long)(kt + bk_) * ldb + col0 + bn];
        }
        __syncthreads();   // protect previous iteration's compute
        As[ak + 0][am] = a4.x;
        As[ak + 1][am] = a4.y;
        As[ak + 2][am] = a4.z;
        As[ak + 3][am] = a4.w;
        if (B_TRANS) {
            Bs[ak + 0][am] = b4.x;
            Bs[ak + 1][am] = b4.y;
            Bs[ak + 2][am] = b4.z;
            Bs[ak + 3][am] = b4.w;
        } else {
            const int bk_ = tid >> 4;
            const int bn  = (tid & 15) * 4;
            *(float4*)&Bs[bk_][bn] = b4;
        }
        __syncthreads();
#pragma unroll
        for (int k = 0; k < TILE_K; ++k) {
            float4 av  = *(const float4*)&As[k][ty * 4];
            float4 bv4 = *(const float4*)&Bs[k][tx * 4];
            float ar[4] = {av.x, av.y, av.z, av.w};
            float br[4] = {bv4.x, bv4.y, bv4.z, bv4.w};
#pragma unroll
            for (int i = 0; i < 4; ++i)
#pragma unroll
                for (int j = 0; j < 4; ++j)
                    acc[i][j] = fmaf(ar[i], br[j], acc[i][j]);
        }
    }

    float4 bias4 = make_float4(0.f, 0.f, 0.f, 0.f);
    if (ADD_BIAS) bias4 = *(const float4*)&bias[col0 + tx * 4];
#pragma unroll
    for (int i = 0; i < 4; ++i) {
        float4 o;
        o.x = acc[i][0] + bias4.x;
        o.y = acc[i][1] + bias4.y;
        o.z = acc[i][2] + bias4.z;
        o.w = acc[i][3] + bias4.w;
        *(float4*)&C[(long)(row0 + ty * 4 + i) * N + col0 + tx * 4] = o;
    }
}

// In-place row softmax over rows of length 1024. One wave per row, 4 rows/block.
__global__ __launch_bounds__(256)
void softmax_rows(float* __restrict__ S)
{
    const long row = (long)blockIdx.x * 4 + (threadIdx.x >> 6);
    const int lane = threadIdx.x & 63;
    float* p = S + row * (long)TENC;

    float4 v[4];
    float m = -INFINITY;
#pragma unroll
    for (int i = 0; i < 4; ++i) {
        v[i] = *(const float4*)&p[i * 256 + lane * 4];
        m = fmaxf(fmaxf(fmaxf(v[i].x, v[i].y), fmaxf(v[i].z, v[i].w)), m);
    }
#pragma unroll
    for (int o = 32; o; o >>= 1) m = fmaxf(m, __shfl_xor(m, o, 64));

    float s = 0.f;
#pragma unroll
    for (int i = 0; i < 4; ++i) {
        v[i].x = __expf(v[i].x - m);
        v[i].y = __expf(v[i].y - m);
        v[i].z = __expf(v[i].z - m);
        v[i].w = __expf(v[i].w - m);
        s += v[i].x + v[i].y + v[i].z + v[i].w;
    }
#pragma unroll
    for (int o = 32; o; o >>= 1) s += __shfl_xor(s, o, 64);

    const float inv = 1.0f / s;
#pragma unroll
    for (int i = 0; i < 4; ++i) {
        v[i].x *= inv; v[i].y *= inv; v[i].z *= inv; v[i].w *= inv;
        *(float4*)&p[i * 256 + lane * 4] = v[i];
    }
}

extern "C" void kernel_launch(void* const* d_in, const int* in_sizes, int n_in,
                              void* d_out, int out_size, void* d_ws, size_t ws_size,
                              hipStream_t stream)
{
    const float* enc = (const float*)d_in[0];   // [32,1024,512]
    const float* dec = (const float*)d_in[1];   // [32,512,512]
    const float* Wk  = (const float*)d_in[2];   // [512,512]
    // bk (d_in[3]) is softmax-shift-invariant -> mathematically drops out
    const float* Wv  = (const float*)d_in[4];   // [512,512]
    const float* bv  = (const float*)d_in[5];   // [512]

    float* ctx  = (float*)d_out;                           // [32,512,512]
    float* attn = ctx + (long)BB * TDEC * NST;             // [32,512,1024]
    float* ws   = (float*)d_ws;                            // 32 MB: Dk, then AE (reused)

    const dim3 blk(256);

    // 1) Dk = dec @ Wk^T   [16384 x 512], K=512
    gemm_f32<true, false><<<dim3(DDIM / TILE_N, (BB * TDEC) / TILE_M, 1), blk, 0, stream>>>(
        dec, Wk, nullptr, ws,
        BB * TDEC, DDIM, NST, NST, NST, 0, 0, 0);

    // 2) score = Dk @ enc^T  per batch  [512 x 1024], K=512 -> into attn region
    gemm_f32<true, false><<<dim3(TENC / TILE_N, TDEC / TILE_M, BB), blk, 0, stream>>>(
        ws, enc, nullptr, attn,
        TDEC, TENC, DDIM, DDIM, DDIM,
        (long)TDEC * DDIM, (long)TENC * DDIM, (long)TDEC * TENC);

    // 3) softmax rows (in place on attn)
    softmax_rows<<<(BB * TDEC) / 4, blk, 0, stream>>>(attn);

    // 4) AE = attn @ enc  per batch  [512 x 512], K=1024 -> into ws (reuse)
    gemm_f32<false, false><<<dim3(DDIM / TILE_N, TDEC / TILE_M, BB), blk, 0, stream>>>(
        attn, enc, nullptr, ws,
        TDEC, DDIM, TENC, TENC, DDIM,
        (long)TDEC * TENC, (long)TENC * DDIM, (long)TDEC * DDIM);

    // 5) ctx = AE @ Wv + bv   [16384 x 512], K=512
    gemm_f32<false, true><<<dim3(NST / TILE_N, (BB * TDEC) / TILE_M, 1), blk, 0, stream>>>(
        ws, Wv, bv, ctx,
        BB * TDEC, NST, DDIM, DDIM, NST, 0, 0, 0);
}

// Round 2
// 245.002 us; speedup vs baseline: 2.9911x; 2.9911x over previous
//
#include <hip/hip_runtime.h>
#include <math.h>

#define BB    32
#define TENC  1024
#define TDEC  512
#define DDIM  512
#define NST   512

typedef __bf16 bf16_t;
typedef __bf16 bf16x8 __attribute__((ext_vector_type(8)));
typedef __bf16 bf16x4 __attribute__((ext_vector_type(4)));
typedef float  f32x4  __attribute__((ext_vector_type(4)));

#define GLOAD_LDS16(gp, lp) __builtin_amdgcn_global_load_lds( \
    (const __attribute__((address_space(1))) unsigned int*)(const void*)(gp), \
    (__attribute__((address_space(3))) unsigned int*)(lp), 16, 0, 0)

// ---------------------------------------------------------------------------
// Split f32 -> bf16 hi/lo (elementwise, float4 vectorized)
__global__ __launch_bounds__(256)
void split_f32_bf16(const float* __restrict__ x, bf16_t* __restrict__ hi,
                    bf16_t* __restrict__ lo, long n4)
{
    long i = (long)blockIdx.x * 256 + threadIdx.x;
    if (i >= n4) return;
    float4 v = *(const float4*)&x[i * 4];
    float f[4] = {v.x, v.y, v.z, v.w};
    bf16x4 h, l;
#pragma unroll
    for (int e = 0; e < 4; ++e) {
        bf16_t hh = (bf16_t)f[e];
        h[e] = hh;
        l[e] = (bf16_t)(f[e] - (float)hh);
    }
    *(bf16x4*)&hi[i * 4] = h;
    *(bf16x4*)&lo[i * 4] = l;
}

// ---------------------------------------------------------------------------
// Tiled transpose: out[c][r] = bf16(in[r][c]); in is [R][C] (f32 or bf16)
template<typename TIN>
__global__ __launch_bounds__(256)
void transpose_to_bf16(const TIN* __restrict__ in, bf16_t* __restrict__ out,
                       int R, int C, long sIn, long sOut)
{
    __shared__ bf16_t tile[64][65];
    const long b = blockIdx.z;
    in  += b * sIn;
    out += b * sOut;
    const int c0 = blockIdx.x * 64, r0 = blockIdx.y * 64;
    const int t = threadIdx.x;
    const int rr = t >> 4;
    const int cc = (t & 15) * 4;
#pragma unroll
    for (int p = 0; p < 4; ++p) {
        int r = rr + p * 16;
        if constexpr (sizeof(TIN) == 4) {
            float4 v = *(const float4*)&in[(long)(r0 + r) * C + c0 + cc];
            tile[r][cc + 0] = (bf16_t)v.x;
            tile[r][cc + 1] = (bf16_t)v.y;
            tile[r][cc + 2] = (bf16_t)v.z;
            tile[r][cc + 3] = (bf16_t)v.w;
        } else {
            bf16x4 v = *(const bf16x4*)&in[(long)(r0 + r) * C + c0 + cc];
            tile[r][cc + 0] = v[0];
            tile[r][cc + 1] = v[1];
            tile[r][cc + 2] = v[2];
            tile[r][cc + 3] = v[3];
        }
    }
    __syncthreads();
    const int dr = t >> 2;
    const int tc = (t & 3) * 16;
    bf16_t tmp[16];
#pragma unroll
    for (int e = 0; e < 16; ++e) tmp[e] = tile[tc + e][dr];
    *(bf16x8*)&out[(long)(c0 + dr) * R + r0 + tc]     = *(bf16x8*)&tmp[0];
    *(bf16x8*)&out[(long)(c0 + dr) * R + r0 + tc + 8] = *(bf16x8*)&tmp[8];
}

// ---------------------------------------------------------------------------
// MFMA GEMM: C[M,N] = A[M,K] @ B'[N,K]^T (both operands K-contiguous rows).
// SPLIT: A,B given as hi+lo pairs; accumulate hi*hi + hi*lo + lo*hi.
// EPI: 0=f32, 1=split bf16 (C0=hi,C1=lo), 2=bf16, 3=f32+bias
template<int SPLIT, int EPI>
__global__ __launch_bounds__(256)
void mfma_gemm(const bf16_t* __restrict__ Ahi, const bf16_t* __restrict__ Alo,
               const bf16_t* __restrict__ Bhi, const bf16_t* __restrict__ Blo,
               const float* __restrict__ bias,
               void* __restrict__ C0, void* __restrict__ C1,
               int M, int N, int K, long sA, long sB, long sC)
{
    __shared__ bf16_t sAh[128 * 32];
    __shared__ bf16_t sBh[128 * 32];
    __shared__ bf16_t sAl[SPLIT ? 128 * 32 : 8];
    __shared__ bf16_t sBl[SPLIT ? 128 * 32 : 8];

    const int tid  = threadIdx.x;
    const int wave = tid >> 6;
    const int lane = tid & 63;
    const long bz  = blockIdx.z;

    const bf16_t* Ah = Ahi + bz * sA;
    const bf16_t* Bh = Bhi + bz * sB;
    const bf16_t* Al = SPLIT ? (Alo + bz * sA) : nullptr;
    const bf16_t* Bl = SPLIT ? (Blo + bz * sB) : nullptr;

    const int row0 = blockIdx.y * 128;
    const int col0 = blockIdx.x * 128;
    const int wr = (wave >> 1) * 64;
    const int wc = (wave & 1) * 64;

    f32x4 acc[4][4] = {};

    const int ldrow = lane >> 2;        // row within 16-row chunk
    const int ldcol = (lane & 3) * 8;   // bf16 col offset
    const int hgrp  = (lane >> 4) * 8;  // k offset for frags
    const int fr    = lane & 15;

    for (int kt = 0; kt < K; kt += 32) {
        __syncthreads();
#pragma unroll
        for (int c = 0; c < 2; ++c) {
            const int chunk = wave * 2 + c;
            const int r = chunk * 16 + ldrow;
            GLOAD_LDS16(Ah + (long)(row0 + r) * K + kt + ldcol, &sAh[chunk * 512]);
            GLOAD_LDS16(Bh + (long)(col0 + r) * K + kt + ldcol, &sBh[chunk * 512]);
            if (SPLIT) {
                GLOAD_LDS16(Al + (long)(row0 + r) * K + kt + ldcol, &sAl[chunk * 512]);
                GLOAD_LDS16(Bl + (long)(col0 + r) * K + kt + ldcol, &sBl[chunk * 512]);
            }
        }
        __syncthreads();

        bf16x8 aH[4], bH[4];
#pragma unroll
        for (int i = 0; i < 4; ++i)
            aH[i] = *(const bf16x8*)&sAh[(wr + i * 16 + fr) * 32 + hgrp];
#pragma unroll
        for (int j = 0; j < 4; ++j)
            bH[j] = *(const bf16x8*)&sBh[(wc + j * 16 + fr) * 32 + hgrp];

        if (SPLIT) {
            bf16x8 aL[4], bL[4];
#pragma unroll
            for (int i = 0; i < 4; ++i)
                aL[i] = *(const bf16x8*)&sAl[(wr + i * 16 + fr) * 32 + hgrp];
#pragma unroll
            for (int j = 0; j < 4; ++j)
                bL[j] = *(const bf16x8*)&sBl[(wc + j * 16 + fr) * 32 + hgrp];
#pragma unroll
            for (int i = 0; i < 4; ++i)
#pragma unroll
                for (int j = 0; j < 4; ++j) {
                    acc[i][j] = __builtin_amdgcn_mfma_f32_16x16x32_bf16(aH[i], bH[j], acc[i][j], 0, 0, 0);
                    acc[i][j] = __builtin_amdgcn_mfma_f32_16x16x32_bf16(aH[i], bL[j], acc[i][j], 0, 0, 0);
                    acc[i][j] = __builtin_amdgcn_mfma_f32_16x16x32_bf16(aL[i], bH[j], acc[i][j], 0, 0, 0);
                }
        } else {
#pragma unroll
            for (int i = 0; i < 4; ++i)
#pragma unroll
                for (int j = 0; j < 4; ++j)
                    acc[i][j] = __builtin_amdgcn_mfma_f32_16x16x32_bf16(aH[i], bH[j], acc[i][j], 0, 0, 0);
        }
    }

    const int frow = (lane >> 4) * 4;
#pragma unroll
    for (int i = 0; i < 4; ++i) {
        const int rg = row0 + wr + i * 16 + frow;
#pragma unroll
        for (int j = 0; j < 4; ++j) {
            const int cg = col0 + wc + j * 16 + fr;
            if constexpr (EPI == 0 || EPI == 3) {
                float* C = (float*)C0 + bz * sC;
                float badd = (EPI == 3) ? bias[cg] : 0.0f;
#pragma unroll
                for (int r = 0; r < 4; ++r)
                    C[(long)(rg + r) * N + cg] = acc[i][j][r] + badd;
            } else if constexpr (EPI == 1) {
                bf16_t* Ch = (bf16_t*)C0 + bz * sC;
                bf16_t* Cl = (bf16_t*)C1 + bz * sC;
#pragma unroll
                for (int r = 0; r < 4; ++r) {
                    float v = acc[i][j][r];
                    bf16_t h = (bf16_t)v;
                    Ch[(long)(rg + r) * N + cg] = h;
                    Cl[(long)(rg + r) * N + cg] = (bf16_t)(v - (float)h);
                }
            } else {
                bf16_t* Ch = (bf16_t*)C0 + bz * sC;
#pragma unroll
                for (int r = 0; r < 4; ++r)
                    Ch[(long)(rg + r) * N + cg] = (bf16_t)acc[i][j][r];
            }
        }
    }
}

// ---------------------------------------------------------------------------
// Row softmax over length-1024 rows, in place (f32) + optional bf16 copy.
__global__ __launch_bounds__(256)
void softmax_rows(float* __restrict__ S, bf16_t* __restrict__ Sb)
{
    const long row = (long)blockIdx.x * 4 + (threadIdx.x >> 6);
    const int lane = threadIdx.x & 63;
    float* p = S + row * (long)TENC;

    float4 v[4];
    float m = -INFINITY;
#pragma unroll
    for (int i = 0; i < 4; ++i) {
        v[i] = *(const float4*)&p[i * 256 + lane * 4];
        m = fmaxf(fmaxf(fmaxf(v[i].x, v[i].y), fmaxf(v[i].z, v[i].w)), m);
    }
#pragma unroll
    for (int o = 32; o; o >>= 1) m = fmaxf(m, __shfl_xor(m, o, 64));

    float s = 0.f;
#pragma unroll
    for (int i = 0; i < 4; ++i) {
        v[i].x = __expf(v[i].x - m);
        v[i].y = __expf(v[i].y - m);
        v[i].z = __expf(v[i].z - m);
        v[i].w = __expf(v[i].w - m);
        s += v[i].x + v[i].y + v[i].z + v[i].w;
    }
#pragma unroll
    for (int o = 32; o; o >>= 1) s += __shfl_xor(s, o, 64);

    const float inv = 1.0f / s;
#pragma unroll
    for (int i = 0; i < 4; ++i) {
        v[i].x *= inv; v[i].y *= inv; v[i].z *= inv; v[i].w *= inv;
        *(float4*)&p[i * 256 + lane * 4] = v[i];
        if (Sb) {
            bf16x4 b;
            b[0] = (bf16_t)v[i].x; b[1] = (bf16_t)v[i].y;
            b[2] = (bf16_t)v[i].z; b[3] = (bf16_t)v[i].w;
            *(bf16x4*)&Sb[row * (long)TENC + i * 256 + lane * 4] = b;
        }
    }
}

// ---------------------------------------------------------------------------
// fp32 fallback GEMM (round-1, kept in case ws_size is small)
#define TILE_M 64
#define TILE_N 64
#define TILE_K 16
template<bool B_TRANS, bool ADD_BIAS>
__global__ __launch_bounds__(256)
void gemm_f32(const float* __restrict__ A, const float* __restrict__ Bm,
              const float* __restrict__ bias, float* __restrict__ C,
              int M, int N, int K, int lda, int ldb,
              long strideA, long strideB, long strideC)
{
    __shared__ float As[TILE_K][TILE_M + 4];
    __shared__ float Bs[TILE_K][TILE_N + 4];
    const int b = blockIdx.z;
    A += (long)b * strideA; Bm += (long)b * strideB; C += (long)b * strideC;
    const int tid = threadIdx.x;
    const int tx = tid & 15, ty = tid >> 4;
    const int row0 = blockIdx.y * TILE_M, col0 = blockIdx.x * TILE_N;
    const int am = tid >> 2, ak = (tid & 3) * 4;
    float acc[4][4] = {};
    for (int kt = 0; kt < K; kt += TILE_K) {
        float4 a4 = *(const float4*)&A[(long)(row0 + am) * lda + kt + ak];
        float4 b4;
        if (B_TRANS) b4 = *(const float4*)&Bm[(long)(col0 + am) * ldb + kt + ak];
        else {
            const int bk_ = tid >> 4, bn = (tid & 15) * 4;
            b4 = *(const float4*)&Bm[(long)(kt + bk_) * ldb + col0 + bn];
        }
        __syncthreads();
        As[ak + 0][am] = a4.x; As[ak + 1][am] = a4.y;
        As[ak + 2][am] = a4.z; As[ak + 3][am] = a4.w;
        if (B_TRANS) {
            Bs[ak + 0][am] = b4.x; Bs[ak + 1][am] = b4.y;
            Bs[ak + 2][am] = b4.z; Bs[ak + 3][am] = b4.w;
        } else {
            const int bk_ = tid >> 4, bn = (tid & 15) * 4;
            *(float4*)&Bs[bk_][bn] = b4;
        }
        __syncthreads();
#pragma unroll
        for (int k = 0; k < TILE_K; ++k) {
            float4 av = *(const float4*)&As[k][ty * 4];
            float4 bv4 = *(const float4*)&Bs[k][tx * 4];
            float ar[4] = {av.x, av.y, av.z, av.w};
            float br[4] = {bv4.x, bv4.y, bv4.z, bv4.w};
#pragma unroll
            for (int i = 0; i < 4; ++i)
#pragma unroll
                for (int j = 0; j < 4; ++j)
                    acc[i][j] = fmaf(ar[i], br[j], acc[i][j]);
        }
    }
    float4 bias4 = make_float4(0.f, 0.f, 0.f, 0.f);
    if (ADD_BIAS) bias4 = *(const float4*)&bias[col0 + tx * 4];
#pragma unroll
    for (int i = 0; i < 4; ++i) {
        float4 o;
        o.x = acc[i][0] + bias4.x; o.y = acc[i][1] + bias4.y;
        o.z = acc[i][2] + bias4.z; o.w = acc[i][3] + bias4.w;
        *(float4*)&C[(long)(row0 + ty * 4 + i) * N + col0 + tx * 4] = o;
    }
}

// ---------------------------------------------------------------------------
extern "C" void kernel_launch(void* const* d_in, const int* in_sizes, int n_in,
                              void* d_out, int out_size, void* d_ws, size_t ws_size,
                              hipStream_t stream)
{
    const float* enc = (const float*)d_in[0];
    const float* dec = (const float*)d_in[1];
    const float* Wk  = (const float*)d_in[2];
    const float* Wv  = (const float*)d_in[4];
    const float* bv  = (const float*)d_in[5];

    const long nE = (long)BB * TENC * DDIM;   // 16777216
    const long nD = (long)BB * TDEC * NST;    // 8388608
    const long nW = (long)DDIM * NST;         // 262144

    float* ctx   = (float*)d_out;             // [32,512,512]
    float* attnF = ctx + nD;                  // [32,512,1024]

    const size_t need = 85458944;
    const dim3 blk(256);

    if (ws_size < need) {
        // fp32 fallback (proven path)
        float* ws = (float*)d_ws;
        gemm_f32<true, false><<<dim3(DDIM / 64, (BB * TDEC) / 64, 1), blk, 0, stream>>>(
            dec, Wk, nullptr, ws, BB * TDEC, DDIM, NST, NST, NST, 0, 0, 0);
        gemm_f32<true, false><<<dim3(TENC / 64, TDEC / 64, BB), blk, 0, stream>>>(
            ws, enc, nullptr, attnF, TDEC, TENC, DDIM, DDIM, DDIM,
            (long)TDEC * DDIM, (long)TENC * DDIM, (long)TDEC * TENC);
        softmax_rows<<<(BB * TDEC) / 4, blk, 0, stream>>>(attnF, nullptr);
        gemm_f32<false, false><<<dim3(DDIM / 64, TDEC / 64, BB), blk, 0, stream>>>(
            attnF, enc, nullptr, ws, TDEC, DDIM, TENC, TENC, DDIM,
            (long)TDEC * TENC, (long)TENC * DDIM, (long)TDEC * DDIM);
        gemm_f32<false, true><<<dim3(NST / 64, (BB * TDEC) / 64, 1), blk, 0, stream>>>(
            ws, Wv, bv, ctx, BB * TDEC, NST, DDIM, DDIM, NST, 0, 0, 0);
        return;
    }

    // ws layout (bytes)
    char* w = (char*)d_ws;
    bf16_t* Ehi  = (bf16_t*)(w);                 // 33.55 MB  (later: attn bf16)
    bf16_t* Elo  = (bf16_t*)(w + 33554432);      // 33.55 MB  (later: enc^T bf16)
    bf16_t* AE   = (bf16_t*)(w + 67108864);      // 16.78 MB
    bf16_t* Wkhi = (bf16_t*)(w + 83886080);
    bf16_t* Wklo = (bf16_t*)(w + 84410368);
    bf16_t* WvT  = (bf16_t*)(w + 84934656);

    // scratch inside d_out (free until the owning GEMM writes it)
    bf16_t* Dhi   = (bf16_t*)attnF;              // dec hi/lo in attn region
    bf16_t* Dlo   = Dhi + nD;
    bf16_t* DKhi  = (bf16_t*)ctx;                // DK hi/lo in ctx region
    bf16_t* DKlo  = DKhi + nD;
    bf16_t* attnB = Ehi;                         // aliases
    bf16_t* ET    = Elo;

    // 1) conversions
    split_f32_bf16<<<(unsigned)((nD / 4 + 255) / 256), blk, 0, stream>>>(dec, Dhi, Dlo, nD / 4);
    split_f32_bf16<<<(unsigned)((nW / 4 + 255) / 256), blk, 0, stream>>>(Wk, Wkhi, Wklo, nW / 4);
    split_f32_bf16<<<(unsigned)((nE / 4 + 255) / 256), blk, 0, stream>>>(enc, Ehi, Elo, nE / 4);
    transpose_to_bf16<float><<<dim3(8, 8, 1), blk, 0, stream>>>(
        Wv, WvT, DDIM, NST, 0, 0);   // WvT[n][d]

    // 2) DK = dec @ Wk^T   (split x split) -> split bf16 into ctx region
    mfma_gemm<1, 1><<<dim3(DDIM / 128, (BB * TDEC) / 128, 1), blk, 0, stream>>>(
        Dhi, Dlo, Wkhi, Wklo, nullptr, DKhi, DKlo,
        BB * TDEC, DDIM, NST, 0, 0, 0);

    // 3) score = DK @ enc^T  (split x split) -> f32 attn region
    mfma_gemm<1, 0><<<dim3(TENC / 128, TDEC / 128, BB), blk, 0, stream>>>(
        DKhi, DKlo, Ehi, Elo, nullptr, attnF, nullptr,
        TDEC, TENC, DDIM,
        (long)TDEC * DDIM, (long)TENC * DDIM, (long)TDEC * TENC);

    // 4) enc^T bf16 (overwrites Elo — no longer needed)
    transpose_to_bf16<bf16_t><<<dim3(DDIM / 64, TENC / 64, BB), blk, 0, stream>>>(
        Ehi, ET, TENC, DDIM, (long)TENC * DDIM, (long)DDIM * TENC);

    // 5) softmax (f32 in place; bf16 copy overwrites Ehi — no longer needed)
    softmax_rows<<<(BB * TDEC) / 4, blk, 0, stream>>>(attnF, attnB);

    // 6) AE = attn @ enc  (plain bf16) -> bf16 ws
    mfma_gemm<0, 2><<<dim3(DDIM / 128, TDEC / 128, BB), blk, 0, stream>>>(
        attnB, nullptr, ET, nullptr, nullptr, AE, nullptr,
        TDEC, DDIM, TENC,
        (long)TDEC * TENC, (long)DDIM * TENC, (long)TDEC * DDIM);

    // 7) ctx = AE @ Wv^T' + bv  (plain bf16) -> f32 ctx (overwrites DK scratch)
    mfma_gemm<0, 3><<<dim3(NST / 128, (BB * TDEC) / 128, 1), blk, 0, stream>>>(
        AE, nullptr, WvT, nullptr, bv, ctx, nullptr,
        BB * TDEC, NST, DDIM, 0, 0, 0);
}

// Round 3
// 233.931 us; speedup vs baseline: 3.1326x; 1.0473x over previous
//
#include <hip/hip_runtime.h>
#include <math.h>

#define BB    32
#define TENC  1024
#define TDEC  512
#define DDIM  512
#define NST   512

typedef __bf16 bf16_t;
typedef __bf16 bf16x8 __attribute__((ext_vector_type(8)));
typedef __bf16 bf16x4 __attribute__((ext_vector_type(4)));
typedef float  f32x4  __attribute__((ext_vector_type(4)));

#define GLOAD_LDS16(gp, lp) __builtin_amdgcn_global_load_lds( \
    (const __attribute__((address_space(1))) unsigned int*)(const void*)(gp), \
    (__attribute__((address_space(3))) unsigned int*)(lp), 16, 0, 0)

static __device__ __forceinline__ f32x4 MFMA16(bf16x8 a, bf16x8 b, f32x4 c) {
    return __builtin_amdgcn_mfma_f32_16x16x32_bf16(a, b, c, 0, 0, 0);
}

// ---------------------------------------------------------------------------
// Split f32 -> bf16 hi/lo
__global__ __launch_bounds__(256)
void split_f32_bf16(const float* __restrict__ x, bf16_t* __restrict__ hi,
                    bf16_t* __restrict__ lo, long n4)
{
    long i = (long)blockIdx.x * 256 + threadIdx.x;
    if (i >= n4) return;
    float4 v = *(const float4*)&x[i * 4];
    float f[4] = {v.x, v.y, v.z, v.w};
    bf16x4 h, l;
#pragma unroll
    for (int e = 0; e < 4; ++e) {
        bf16_t hh = (bf16_t)f[e];
        h[e] = hh;
        l[e] = (bf16_t)(f[e] - (float)hh);
    }
    *(bf16x4*)&hi[i * 4] = h;
    *(bf16x4*)&lo[i * 4] = l;
}

// ---------------------------------------------------------------------------
// Tiled transpose: out[c][r] = bf16(in[r][c])
template<typename TIN>
__global__ __launch_bounds__(256)
void transpose_to_bf16(const TIN* __restrict__ in, bf16_t* __restrict__ out,
                       int R, int C, long sIn, long sOut)
{
    __shared__ bf16_t tile[64][65];
    const long b = blockIdx.z;
    in  += b * sIn;
    out += b * sOut;
    const int c0 = blockIdx.x * 64, r0 = blockIdx.y * 64;
    const int t = threadIdx.x;
    const int rr = t >> 4;
    const int cc = (t & 15) * 4;
#pragma unroll
    for (int p = 0; p < 4; ++p) {
        int r = rr + p * 16;
        if constexpr (sizeof(TIN) == 4) {
            float4 v = *(const float4*)&in[(long)(r0 + r) * C + c0 + cc];
            tile[r][cc + 0] = (bf16_t)v.x;
            tile[r][cc + 1] = (bf16_t)v.y;
            tile[r][cc + 2] = (bf16_t)v.z;
            tile[r][cc + 3] = (bf16_t)v.w;
        } else {
            bf16x4 v = *(const bf16x4*)&in[(long)(r0 + r) * C + c0 + cc];
            tile[r][cc + 0] = v[0];
            tile[r][cc + 1] = v[1];
            tile[r][cc + 2] = v[2];
            tile[r][cc + 3] = v[3];
        }
    }
    __syncthreads();
    const int dr = t >> 2;
    const int tc = (t & 3) * 16;
    bf16_t tmp[16];
#pragma unroll
    for (int e = 0; e < 16; ++e) tmp[e] = tile[tc + e][dr];
    *(bf16x8*)&out[(long)(c0 + dr) * R + r0 + tc]     = *(bf16x8*)&tmp[0];
    *(bf16x8*)&out[(long)(c0 + dr) * R + r0 + tc + 8] = *(bf16x8*)&tmp[8];
}

// ---------------------------------------------------------------------------
// Phased split GEMM: C[M,N] = (Ahi+Alo)[M,K] @ ((Bhi+Blo)[N,K])^T, dropping lo*lo.
// BM=128, BN=256, BK=32, 8 waves (512 thr), double-buffered swizzled LDS (96KB).
// Counted vmcnt (T4), per-phase barriers + setprio (T3/T5), XOR slot swizzle (T2),
// bijective XCD swizzle (T1). EPI: 0 = f32 out, 1 = split bf16 out (C0=hi,C1=lo).
template<int EPI>
__global__ __launch_bounds__(512, 1)
void gemm_split8(const bf16_t* __restrict__ Ahi, const bf16_t* __restrict__ Alo,
                 const bf16_t* __restrict__ Bhi, const bf16_t* __restrict__ Blo,
                 void* __restrict__ C0, void* __restrict__ C1,
                 int M, int N, int K, long sA, long sB, long sC)
{
    // per buffer (bf16 elems): Ah[0,4096) Al[4096,8192) Bh[8192,16384) Bl[16384,24576)
    __shared__ bf16_t lds[2][24576];

    const int tid  = threadIdx.x;
    const int wave = tid >> 6;
    const int lane = tid & 63;

    // T1: bijective XCD swizzle (grid sizes are multiples of 8)
    const int gx = gridDim.x, gy = gridDim.y;
    const long nwg = (long)gx * gy * gridDim.z;
    const long f  = ((long)blockIdx.z * gy + blockIdx.y) * gx + blockIdx.x;
    const long f2 = (f & 7) * (nwg >> 3) + (f >> 3);
    const int bx  = (int)(f2 % gx);
    const int by  = (int)((f2 / gx) % gy);
    const long bz = f2 / ((long)gx * gy);

    const bf16_t* Ah = Ahi + bz * sA;
    const bf16_t* Al = Alo + bz * sA;
    const bf16_t* Bh = Bhi + bz * sB;
    const bf16_t* Bl = Blo + bz * sB;

    const int row0 = by * 128;
    const int col0 = bx * 256;

    // staging: per issue, 512 threads cover 128 rows x 32 bf16 (8KB), 16B/lane.
    // LDS dest linear; global slot pre-swizzled (rule #21).
    const int srow  = wave * 16 + (lane >> 2);
    const int sslot = (lane & 3) ^ ((srow >> 1) & 3);
    const long aOff  = (long)(row0 + srow) * K + sslot * 8;
    const long bOff0 = (long)(col0 + srow) * K + sslot * 8;
    const long bOff1 = (long)(col0 + 128 + srow) * K + sslot * 8;
    const int ldsW = wave * 512;   // elems: wave-uniform LDS chunk base

    // fragment read offsets (swizzled)
    const int fr = lane & 15;
    const int q  = lane >> 4;
    int aro[4], bro[4];
#pragma unroll
    for (int i = 0; i < 4; ++i) {
        const int r = (wave >> 2) * 64 + i * 16 + fr;
        aro[i] = r * 32 + ((q ^ ((r >> 1) & 3)) * 8);
    }
#pragma unroll
    for (int j = 0; j < 4; ++j) {
        const int r = (wave & 3) * 64 + j * 16 + fr;
        bro[j] = r * 32 + ((q ^ ((r >> 1) & 3)) * 8);
    }

    f32x4 acc[4][4] = {};
    const int NT = K >> 5;

#define ISSUE(dst, roff, gptr) GLOAD_LDS16((gptr), &(dst)[(roff) + ldsW])

    // prologue: tile 0 -> buf 0 (6 issues)
    {
        bf16_t* b0 = lds[0];
        ISSUE(b0, 0,     Ah + aOff);
        ISSUE(b0, 4096,  Al + aOff);
        ISSUE(b0, 8192,  Bh + bOff0);
        ISSUE(b0, 12288, Bh + bOff1);
        ISSUE(b0, 16384, Bl + bOff0);
        ISSUE(b0, 20480, Bl + bOff1);
    }

    for (int t = 0; t < NT; ++t) {
        bf16_t* cur = lds[t & 1];
        bf16_t* nxt = lds[(t & 1) ^ 1];
        const int ktn = (t + 1) << 5;
        const bool pf = (t + 1 < NT);
        if (pf) {
            ISSUE(nxt, 0,    Ah + aOff + ktn);
            ISSUE(nxt, 4096, Al + aOff + ktn);
            asm volatile("s_waitcnt vmcnt(2)");
        } else {
            asm volatile("s_waitcnt vmcnt(0)");
        }
        __builtin_amdgcn_s_barrier();
        __builtin_amdgcn_sched_barrier(0);

        bf16x8 aH[4], aL[4];
#pragma unroll
        for (int i = 0; i < 4; ++i) {
            aH[i] = *(const bf16x8*)&cur[aro[i]];
            aL[i] = *(const bf16x8*)&cur[4096 + aro[i]];
        }
#pragma unroll
        for (int j = 0; j < 4; ++j) {
            bf16x8 bH = *(const bf16x8*)&cur[8192  + bro[j]];
            bf16x8 bL = *(const bf16x8*)&cur[16384 + bro[j]];
            if (pf) {
                if (j == 0)      { ISSUE(nxt, 8192,  Bh + bOff0 + ktn); }
                else if (j == 1) { ISSUE(nxt, 12288, Bh + bOff1 + ktn); }
                else if (j == 2) { ISSUE(nxt, 16384, Bl + bOff0 + ktn); }
                else             { ISSUE(nxt, 20480, Bl + bOff1 + ktn); }
            }
            __builtin_amdgcn_s_barrier();
            __builtin_amdgcn_s_setprio(1);
#pragma unroll
            for (int i = 0; i < 4; ++i) {
                acc[i][j] = MFMA16(aH[i], bH, acc[i][j]);
                acc[i][j] = MFMA16(aH[i], bL, acc[i][j]);
                acc[i][j] = MFMA16(aL[i], bH, acc[i][j]);
            }
            __builtin_amdgcn_s_setprio(0);
            __builtin_amdgcn_sched_barrier(0);
            __builtin_amdgcn_s_barrier();
        }
    }
#undef ISSUE

    // epilogue (C/D layout: col = lane&15, row = (lane>>4)*4 + reg)
    const int frow = q * 4;
#pragma unroll
    for (int i = 0; i < 4; ++i) {
        const int rg = row0 + (wave >> 2) * 64 + i * 16 + frow;
#pragma unroll
        for (int j = 0; j < 4; ++j) {
            const int cg = col0 + (wave & 3) * 64 + j * 16 + fr;
            if constexpr (EPI == 0) {
                float* C = (float*)C0 + bz * sC;
#pragma unroll
                for (int r = 0; r < 4; ++r)
                    C[(long)(rg + r) * N + cg] = acc[i][j][r];
            } else {
                bf16_t* Ch = (bf16_t*)C0 + bz * sC;
                bf16_t* Cl = (bf16_t*)C1 + bz * sC;
#pragma unroll
                for (int r = 0; r < 4; ++r) {
                    float v = acc[i][j][r];
                    bf16_t h = (bf16_t)v;
                    Ch[(long)(rg + r) * N + cg] = h;
                    Cl[(long)(rg + r) * N + cg] = (bf16_t)(v - (float)h);
                }
            }
        }
    }
}

// ---------------------------------------------------------------------------
// Plain bf16 MFMA GEMM (proven R2 structure) for the value chain.
// EPI: 2=bf16 out, 3=f32+bias out
template<int EPI>
__global__ __launch_bounds__(256)
void mfma_gemm(const bf16_t* __restrict__ Ahi, const bf16_t* __restrict__ Bhi,
               const float* __restrict__ bias,
               void* __restrict__ C0,
               int M, int N, int K, long sA, long sB, long sC)
{
    __shared__ bf16_t sAh[128 * 32];
    __shared__ bf16_t sBh[128 * 32];

    const int tid  = threadIdx.x;
    const int wave = tid >> 6;
    const int lane = tid & 63;
    const long bz  = blockIdx.z;

    const bf16_t* Ah = Ahi + bz * sA;
    const bf16_t* Bh = Bhi + bz * sB;

    const int row0 = blockIdx.y * 128;
    const int col0 = blockIdx.x * 128;
    const int wr = (wave >> 1) * 64;
    const int wc = (wave & 1) * 64;

    f32x4 acc[4][4] = {};

    const int ldrow = lane >> 2;
    const int ldcol = (lane & 3) * 8;
    const int hgrp  = (lane >> 4) * 8;
    const int fr    = lane & 15;

    for (int kt = 0; kt < K; kt += 32) {
        __syncthreads();
#pragma unroll
        for (int c = 0; c < 2; ++c) {
            const int chunk = wave * 2 + c;
            const int r = chunk * 16 + ldrow;
            GLOAD_LDS16(Ah + (long)(row0 + r) * K + kt + ldcol, &sAh[chunk * 512]);
            GLOAD_LDS16(Bh + (long)(col0 + r) * K + kt + ldcol, &sBh[chunk * 512]);
        }
        __syncthreads();

        bf16x8 aH[4], bH[4];
#pragma unroll
        for (int i = 0; i < 4; ++i)
            aH[i] = *(const bf16x8*)&sAh[(wr + i * 16 + fr) * 32 + hgrp];
#pragma unroll
        for (int j = 0; j < 4; ++j)
            bH[j] = *(const bf16x8*)&sBh[(wc + j * 16 + fr) * 32 + hgrp];
#pragma unroll
        for (int i = 0; i < 4; ++i)
#pragma unroll
            for (int j = 0; j < 4; ++j)
                acc[i][j] = MFMA16(aH[i], bH[j], acc[i][j]);
    }

    const int frow = (lane >> 4) * 4;
#pragma unroll
    for (int i = 0; i < 4; ++i) {
        const int rg = row0 + wr + i * 16 + frow;
#pragma unroll
        for (int j = 0; j < 4; ++j) {
            const int cg = col0 + wc + j * 16 + fr;
            if constexpr (EPI == 3) {
                float* C = (float*)C0 + bz * sC;
                const float badd = bias[cg];
#pragma unroll
                for (int r = 0; r < 4; ++r)
                    C[(long)(rg + r) * N + cg] = acc[i][j][r] + badd;
            } else {
                bf16_t* Ch = (bf16_t*)C0 + bz * sC;
#pragma unroll
                for (int r = 0; r < 4; ++r)
                    Ch[(long)(rg + r) * N + cg] = (bf16_t)acc[i][j][r];
            }
        }
    }
}

// ---------------------------------------------------------------------------
// Row softmax over length-1024 rows, in place (f32) + bf16 copy.
__global__ __launch_bounds__(256)
void softmax_rows(float* __restrict__ S, bf16_t* __restrict__ Sb)
{
    const long row = (long)blockIdx.x * 4 + (threadIdx.x >> 6);
    const int lane = threadIdx.x & 63;
    float* p = S + row * (long)TENC;

    float4 v[4];
    float m = -INFINITY;
#pragma unroll
    for (int i = 0; i < 4; ++i) {
        v[i] = *(const float4*)&p[i * 256 + lane * 4];
        m = fmaxf(fmaxf(fmaxf(v[i].x, v[i].y), fmaxf(v[i].z, v[i].w)), m);
    }
#pragma unroll
    for (int o = 32; o; o >>= 1) m = fmaxf(m, __shfl_xor(m, o, 64));

    float s = 0.f;
#pragma unroll
    for (int i = 0; i < 4; ++i) {
        v[i].x = __expf(v[i].x - m);
        v[i].y = __expf(v[i].y - m);
        v[i].z = __expf(v[i].z - m);
        v[i].w = __expf(v[i].w - m);
        s += v[i].x + v[i].y + v[i].z + v[i].w;
    }
#pragma unroll
    for (int o = 32; o; o >>= 1) s += __shfl_xor(s, o, 64);

    const float inv = 1.0f / s;
#pragma unroll
    for (int i = 0; i < 4; ++i) {
        v[i].x *= inv; v[i].y *= inv; v[i].z *= inv; v[i].w *= inv;
        *(float4*)&p[i * 256 + lane * 4] = v[i];
        if (Sb) {
            bf16x4 b;
            b[0] = (bf16_t)v[i].x; b[1] = (bf16_t)v[i].y;
            b[2] = (bf16_t)v[i].z; b[3] = (bf16_t)v[i].w;
            *(bf16x4*)&Sb[row * (long)TENC + i * 256 + lane * 4] = b;
        }
    }
}

// ---------------------------------------------------------------------------
// fp32 fallback GEMM (kept as ws-size safety net)
#define TILE_M 64
#define TILE_N 64
#define TILE_K 16
template<bool B_TRANS, bool ADD_BIAS>
__global__ __launch_bounds__(256)
void gemm_f32(const float* __restrict__ A, const float* __restrict__ Bm,
              const float* __restrict__ bias, float* __restrict__ C,
              int M, int N, int K, int lda, int ldb,
              long strideA, long strideB, long strideC)
{
    __shared__ float As[TILE_K][TILE_M + 4];
    __shared__ float Bs[TILE_K][TILE_N + 4];
    const int b = blockIdx.z;
    A += (long)b * strideA; Bm += (long)b * strideB; C += (long)b * strideC;
    const int tid = threadIdx.x;
    const int tx = tid & 15, ty = tid >> 4;
    const int row0 = blockIdx.y * TILE_M, col0 = blockIdx.x * TILE_N;
    const int am = tid >> 2, ak = (tid & 3) * 4;
    float acc[4][4] = {};
    for (int kt = 0; kt < K; kt += TILE_K) {
        float4 a4 = *(const float4*)&A[(long)(row0 + am) * lda + kt + ak];
        float4 b4;
        if (B_TRANS) b4 = *(const float4*)&Bm[(long)(col0 + am) * ldb + kt + ak];
        else {
            const int bk_ = tid >> 4, bn = (tid & 15) * 4;
            b4 = *(const float4*)&Bm[(long)(kt + bk_) * ldb + col0 + bn];
        }
        __syncthreads();
        As[ak + 0][am] = a4.x; As[ak + 1][am] = a4.y;
        As[ak + 2][am] = a4.z; As[ak + 3][am] = a4.w;
        if (B_TRANS) {
            Bs[ak + 0][am] = b4.x; Bs[ak + 1][am] = b4.y;
            Bs[ak + 2][am] = b4.z; Bs[ak + 3][am] = b4.w;
        } else {
            const int bk_ = tid >> 4, bn = (tid & 15) * 4;
            *(float4*)&Bs[bk_][bn] = b4;
        }
        __syncthreads();
#pragma unroll
        for (int k = 0; k < TILE_K; ++k) {
            float4 av = *(const float4*)&As[k][ty * 4];
            float4 bv4 = *(const float4*)&Bs[k][tx * 4];
            float ar[4] = {av.x, av.y, av.z, av.w};
            float br[4] = {bv4.x, bv4.y, bv4.z, bv4.w};
#pragma unroll
            for (int i = 0; i < 4; ++i)
#pragma unroll
                for (int j = 0; j < 4; ++j)
                    acc[i][j] = fmaf(ar[i], br[j], acc[i][j]);
        }
    }
    float4 bias4 = make_float4(0.f, 0.f, 0.f, 0.f);
    if (ADD_BIAS) bias4 = *(const float4*)&bias[col0 + tx * 4];
#pragma unroll
    for (int i = 0; i < 4; ++i) {
        float4 o;
        o.x = acc[i][0] + bias4.x; o.y = acc[i][1] + bias4.y;
        o.z = acc[i][2] + bias4.z; o.w = acc[i][3] + bias4.w;
        *(float4*)&C[(long)(row0 + ty * 4 + i) * N + col0 + tx * 4] = o;
    }
}

// ---------------------------------------------------------------------------
extern "C" void kernel_launch(void* const* d_in, const int* in_sizes, int n_in,
                              void* d_out, int out_size, void* d_ws, size_t ws_size,
                              hipStream_t stream)
{
    const float* enc = (const float*)d_in[0];
    const float* dec = (const float*)d_in[1];
    const float* Wk  = (const float*)d_in[2];
    const float* Wv  = (const float*)d_in[4];
    const float* bv  = (const float*)d_in[5];

    const long nE = (long)BB * TENC * DDIM;   // 16777216
    const long nD = (long)BB * TDEC * NST;    // 8388608
    const long nW = (long)DDIM * NST;         // 262144

    float* ctx   = (float*)d_out;             // [32,512,512]
    float* attnF = ctx + nD;                  // [32,512,1024]

    const size_t need = 85458944;
    const dim3 blk(256);

    if (ws_size < need) {
        float* ws = (float*)d_ws;
        gemm_f32<true, false><<<dim3(DDIM / 64, (BB * TDEC) / 64, 1), blk, 0, stream>>>(
            dec, Wk, nullptr, ws, BB * TDEC, DDIM, NST, NST, NST, 0, 0, 0);
        gemm_f32<true, false><<<dim3(TENC / 64, TDEC / 64, BB), blk, 0, stream>>>(
            ws, enc, nullptr, attnF, TDEC, TENC, DDIM, DDIM, DDIM,
            (long)TDEC * DDIM, (long)TENC * DDIM, (long)TDEC * TENC);
        softmax_rows<<<(BB * TDEC) / 4, blk, 0, stream>>>(attnF, nullptr);
        gemm_f32<false, false><<<dim3(DDIM / 64, TDEC / 64, BB), blk, 0, stream>>>(
            attnF, enc, nullptr, ws, TDEC, DDIM, TENC, TENC, DDIM,
            (long)TDEC * TENC, (long)TENC * DDIM, (long)TDEC * DDIM);
        gemm_f32<false, true><<<dim3(NST / 64, (BB * TDEC) / 64, 1), blk, 0, stream>>>(
            ws, Wv, bv, ctx, BB * TDEC, NST, DDIM, DDIM, NST, 0, 0, 0);
        return;
    }

    // ws layout (bytes)
    char* w = (char*)d_ws;
    bf16_t* Ehi  = (bf16_t*)(w);                 // later aliased: attn bf16
    bf16_t* Elo  = (bf16_t*)(w + 33554432);      // later aliased: enc^T bf16
    bf16_t* AE   = (bf16_t*)(w + 67108864);
    bf16_t* Wkhi = (bf16_t*)(w + 83886080);
    bf16_t* Wklo = (bf16_t*)(w + 84410368);
    bf16_t* WvT  = (bf16_t*)(w + 84934656);

    // scratch inside d_out (free until the owning GEMM writes it)
    bf16_t* Dhi   = (bf16_t*)attnF;              // dec hi/lo in attn region
    bf16_t* Dlo   = Dhi + nD;
    bf16_t* DKhi  = (bf16_t*)ctx;                // DK hi/lo in ctx region
    bf16_t* DKlo  = DKhi + nD;
    bf16_t* attnB = Ehi;
    bf16_t* ET    = Elo;

    // 1) conversions
    split_f32_bf16<<<(unsigned)((nD / 4 + 255) / 256), blk, 0, stream>>>(dec, Dhi, Dlo, nD / 4);
    split_f32_bf16<<<(unsigned)((nW / 4 + 255) / 256), blk, 0, stream>>>(Wk, Wkhi, Wklo, nW / 4);
    split_f32_bf16<<<(unsigned)((nE / 4 + 255) / 256), blk, 0, stream>>>(enc, Ehi, Elo, nE / 4);
    transpose_to_bf16<float><<<dim3(8, 8, 1), blk, 0, stream>>>(
        Wv, WvT, DDIM, NST, 0, 0);

    // 2) DK = dec @ Wk^T   (split x split, phased) -> split bf16 into ctx region
    gemm_split8<1><<<dim3(DDIM / 256, (BB * TDEC) / 128, 1), dim3(512), 0, stream>>>(
        Dhi, Dlo, Wkhi, Wklo, DKhi, DKlo,
        BB * TDEC, DDIM, NST, 0, 0, 0);

    // 3) score = DK @ enc^T  (split x split, phased) -> f32 attn region
    gemm_split8<0><<<dim3(TENC / 256, TDEC / 128, BB), dim3(512), 0, stream>>>(
        DKhi, DKlo, Ehi, Elo, attnF, nullptr,
        TDEC, TENC, DDIM,
        (long)TDEC * DDIM, (long)TENC * DDIM, (long)TDEC * TENC);

    // 4) enc^T bf16 (overwrites Elo — dead after score GEMM)
    transpose_to_bf16<bf16_t><<<dim3(DDIM / 64, TENC / 64, BB), blk, 0, stream>>>(
        Ehi, ET, TENC, DDIM, (long)TENC * DDIM, (long)DDIM * TENC);

    // 5) softmax (f32 in place; bf16 copy overwrites Ehi — dead)
    softmax_rows<<<(BB * TDEC) / 4, blk, 0, stream>>>(attnF, attnB);

    // 6) AE = attn @ enc  (plain bf16) -> bf16 ws
    mfma_gemm<2><<<dim3(DDIM / 128, TDEC / 128, BB), blk, 0, stream>>>(
        attnB, ET, nullptr, AE,
        TDEC, DDIM, TENC,
        (long)TDEC * TENC, (long)DDIM * TENC, (long)TDEC * DDIM);

    // 7) ctx = AE @ Wv^T' + bv  (plain bf16) -> f32 ctx
    mfma_gemm<3><<<dim3(NST / 128, (BB * TDEC) / 128, 1), blk, 0, stream>>>(
        AE, WvT, bv, ctx,
        BB * TDEC, NST, DDIM, 0, 0, 0);
}

// Round 4
// 231.659 us; speedup vs baseline: 3.1634x; 1.0098x over previous
//
#include <hip/hip_runtime.h>
#include <math.h>

#define BB    32
#define TENC  1024
#define TDEC  512
#define DDIM  512
#define NST   512

typedef __bf16 bf16_t;
typedef __bf16 bf16x8 __attribute__((ext_vector_type(8)));
typedef __bf16 bf16x4 __attribute__((ext_vector_type(4)));
typedef float  f32x4  __attribute__((ext_vector_type(4)));

#define GLOAD_LDS16(gp, lp) __builtin_amdgcn_global_load_lds( \
    (const __attribute__((address_space(1))) unsigned int*)(const void*)(gp), \
    (__attribute__((address_space(3))) unsigned int*)(lp), 16, 0, 0)

static __device__ __forceinline__ f32x4 MFMA16(bf16x8 a, bf16x8 b, f32x4 c) {
    return __builtin_amdgcn_mfma_f32_16x16x32_bf16(a, b, c, 0, 0, 0);
}

// ---------------------------------------------------------------------------
// Split f32 -> bf16 hi/lo
__global__ __launch_bounds__(256)
void split_f32_bf16(const float* __restrict__ x, bf16_t* __restrict__ hi,
                    bf16_t* __restrict__ lo, long n4)
{
    long i = (long)blockIdx.x * 256 + threadIdx.x;
    if (i >= n4) return;
    float4 v = *(const float4*)&x[i * 4];
    float f[4] = {v.x, v.y, v.z, v.w};
    bf16x4 h, l;
#pragma unroll
    for (int e = 0; e < 4; ++e) {
        bf16_t hh = (bf16_t)f[e];
        h[e] = hh;
        l[e] = (bf16_t)(f[e] - (float)hh);
    }
    *(bf16x4*)&hi[i * 4] = h;
    *(bf16x4*)&lo[i * 4] = l;
}

// ---------------------------------------------------------------------------
// Tiled transpose: out[c][r] = bf16(in[r][c])
template<typename TIN>
__global__ __launch_bounds__(256)
void transpose_to_bf16(const TIN* __restrict__ in, bf16_t* __restrict__ out,
                       int R, int C, long sIn, long sOut)
{
    __shared__ bf16_t tile[64][65];
    const long b = blockIdx.z;
    in  += b * sIn;
    out += b * sOut;
    const int c0 = blockIdx.x * 64, r0 = blockIdx.y * 64;
    const int t = threadIdx.x;
    const int rr = t >> 4;
    const int cc = (t & 15) * 4;
#pragma unroll
    for (int p = 0; p < 4; ++p) {
        int r = rr + p * 16;
        if constexpr (sizeof(TIN) == 4) {
            float4 v = *(const float4*)&in[(long)(r0 + r) * C + c0 + cc];
            tile[r][cc + 0] = (bf16_t)v.x;
            tile[r][cc + 1] = (bf16_t)v.y;
            tile[r][cc + 2] = (bf16_t)v.z;
            tile[r][cc + 3] = (bf16_t)v.w;
        } else {
            bf16x4 v = *(const bf16x4*)&in[(long)(r0 + r) * C + c0 + cc];
            tile[r][cc + 0] = v[0];
            tile[r][cc + 1] = v[1];
            tile[r][cc + 2] = v[2];
            tile[r][cc + 3] = v[3];
        }
    }
    __syncthreads();
    const int dr = t >> 2;
    const int tc = (t & 3) * 16;
    bf16_t tmp[16];
#pragma unroll
    for (int e = 0; e < 16; ++e) tmp[e] = tile[tc + e][dr];
    *(bf16x8*)&out[(long)(c0 + dr) * R + r0 + tc]     = *(bf16x8*)&tmp[0];
    *(bf16x8*)&out[(long)(c0 + dr) * R + r0 + tc + 8] = *(bf16x8*)&tmp[8];
}

// ---------------------------------------------------------------------------
// Phased split GEMM: C[M,N] = (Ahi+Alo)[M,K] @ ((Bhi+Blo)[N,K])^T, dropping lo*lo.
// BM=128, BN=256, BK=32, 8 waves, double-buffered swizzled LDS (96KB).
// 2 barriers/K-tile; counted vmcnt(6) (T4) so prefetch loads span the whole tile;
// setprio around the 48-MFMA cluster (T5); XOR slot swizzle (T2); XCD swizzle (T1).
// EPI: 0 = f32 out, 1 = split bf16 out (C0=hi,C1=lo).
template<int EPI>
__global__ __launch_bounds__(512, 2)
void gemm_split8(const bf16_t* __restrict__ Ahi, const bf16_t* __restrict__ Alo,
                 const bf16_t* __restrict__ Bhi, const bf16_t* __restrict__ Blo,
                 void* __restrict__ C0, void* __restrict__ C1,
                 int M, int N, int K, long sA, long sB, long sC)
{
    // per buffer (bf16 elems): Ah[0,4096) Al[4096,8192) Bh[8192,16384) Bl[16384,24576)
    __shared__ bf16_t lds[2][24576];

    const int tid  = threadIdx.x;
    const int wave = tid >> 6;
    const int lane = tid & 63;

    // T1: bijective XCD swizzle (grid sizes are multiples of 8)
    const int gx = gridDim.x, gy = gridDim.y;
    const long nwg = (long)gx * gy * gridDim.z;
    const long f  = ((long)blockIdx.z * gy + blockIdx.y) * gx + blockIdx.x;
    const long f2 = (f & 7) * (nwg >> 3) + (f >> 3);
    const int bx  = (int)(f2 % gx);
    const int by  = (int)((f2 / gx) % gy);
    const long bz = f2 / ((long)gx * gy);

    const bf16_t* Ah = Ahi + bz * sA;
    const bf16_t* Al = Alo + bz * sA;
    const bf16_t* Bh = Bhi + bz * sB;
    const bf16_t* Bl = Blo + bz * sB;

    const int row0 = by * 128;
    const int col0 = bx * 256;

    // staging: 512 threads cover 128 rows x 32 bf16 (8KB) per issue, 16B/lane.
    // LDS dest linear (wave chunk + lane*16B); global slot pre-swizzled (rule #21).
    const int srow  = wave * 16 + (lane >> 2);
    const int sslot = (lane & 3) ^ ((srow >> 1) & 3);
    const long aOff  = (long)(row0 + srow) * K + sslot * 8;
    const long bOff0 = (long)(col0 + srow) * K + sslot * 8;
    const long bOff1 = (long)(col0 + 128 + srow) * K + sslot * 8;
    const int ldsW = wave * 512;   // elems: wave-uniform LDS chunk base

    // fragment read offsets (swizzled to match)
    const int fr = lane & 15;
    const int q  = lane >> 4;
    int aro[4], bro[4];
#pragma unroll
    for (int i = 0; i < 4; ++i) {
        const int r = (wave >> 2) * 64 + i * 16 + fr;
        aro[i] = r * 32 + ((q ^ ((r >> 1) & 3)) * 8);
    }
#pragma unroll
    for (int j = 0; j < 4; ++j) {
        const int r = (wave & 3) * 64 + j * 16 + fr;
        bro[j] = r * 32 + ((q ^ ((r >> 1) & 3)) * 8);
    }

    f32x4 acc[4][4] = {};
    const int NT = K >> 5;

#define ISSUE(dst, roff, gptr) GLOAD_LDS16((gptr), &(dst)[(roff) + ldsW])

    // prologue: tile 0 -> buf 0 (6 issues)
    {
        bf16_t* b0 = lds[0];
        ISSUE(b0, 0,     Ah + aOff);
        ISSUE(b0, 4096,  Al + aOff);
        ISSUE(b0, 8192,  Bh + bOff0);
        ISSUE(b0, 12288, Bh + bOff1);
        ISSUE(b0, 16384, Bl + bOff0);
        ISSUE(b0, 20480, Bl + bOff1);
    }

    for (int t = 0; t < NT; ++t) {
        bf16_t* cur = lds[t & 1];
        bf16_t* nxt = lds[(t & 1) ^ 1];
        const int ktn = (t + 1) << 5;
        const bool pf = (t + 1 < NT);

        __builtin_amdgcn_sched_barrier(0);
        __builtin_amdgcn_s_barrier();          // all waves done READING nxt (prev tile frags)
        if (pf) {
            ISSUE(nxt, 0,     Ah + aOff + ktn);
            ISSUE(nxt, 4096,  Al + aOff + ktn);
            ISSUE(nxt, 8192,  Bh + bOff0 + ktn);
            ISSUE(nxt, 12288, Bh + bOff1 + ktn);
            ISSUE(nxt, 16384, Bl + bOff0 + ktn);
            ISSUE(nxt, 20480, Bl + bOff1 + ktn);
            asm volatile("s_waitcnt vmcnt(6)" ::: "memory");   // tile t landed; 6 newest in flight
        } else {
            asm volatile("s_waitcnt vmcnt(0)" ::: "memory");
        }
        __builtin_amdgcn_s_barrier();          // every wave's tile-t chunk landed
        __builtin_amdgcn_sched_barrier(0);

        bf16x8 aH[4], aL[4], bH[4], bL[4];
#pragma unroll
        for (int i = 0; i < 4; ++i) {
            aH[i] = *(const bf16x8*)&cur[aro[i]];
            aL[i] = *(const bf16x8*)&cur[4096 + aro[i]];
        }
#pragma unroll
        for (int j = 0; j < 4; ++j) {
            bH[j] = *(const bf16x8*)&cur[8192  + bro[j]];
            bL[j] = *(const bf16x8*)&cur[16384 + bro[j]];
        }

        __builtin_amdgcn_s_setprio(1);
#pragma unroll
        for (int j = 0; j < 4; ++j)
#pragma unroll
            for (int i = 0; i < 4; ++i) {
                acc[i][j] = MFMA16(aH[i], bH[j], acc[i][j]);
                acc[i][j] = MFMA16(aH[i], bL[j], acc[i][j]);
                acc[i][j] = MFMA16(aL[i], bH[j], acc[i][j]);
            }
        __builtin_amdgcn_s_setprio(0);
    }
#undef ISSUE

    // epilogue (C/D layout: col = lane&15, row = (lane>>4)*4 + reg)
    const int frow = q * 4;
#pragma unroll
    for (int i = 0; i < 4; ++i) {
        const int rg = row0 + (wave >> 2) * 64 + i * 16 + frow;
#pragma unroll
        for (int j = 0; j < 4; ++j) {
            const int cg = col0 + (wave & 3) * 64 + j * 16 + fr;
            if constexpr (EPI == 0) {
                float* C = (float*)C0 + bz * sC;
#pragma unroll
                for (int r = 0; r < 4; ++r)
                    C[(long)(rg + r) * N + cg] = acc[i][j][r];
            } else {
                bf16_t* Ch = (bf16_t*)C0 + bz * sC;
                bf16_t* Cl = (bf16_t*)C1 + bz * sC;
#pragma unroll
                for (int r = 0; r < 4; ++r) {
                    float v = acc[i][j][r];
                    bf16_t h = (bf16_t)v;
                    Ch[(long)(rg + r) * N + cg] = h;
                    Cl[(long)(rg + r) * N + cg] = (bf16_t)(v - (float)h);
                }
            }
        }
    }
}

// ---------------------------------------------------------------------------
// Plain bf16 MFMA GEMM (proven m97-style; 3 blocks/CU occupancy) — value chain.
// EPI: 2=bf16 out, 3=f32+bias out
template<int EPI>
__global__ __launch_bounds__(256)
void mfma_gemm(const bf16_t* __restrict__ Ahi, const bf16_t* __restrict__ Bhi,
               const float* __restrict__ bias,
               void* __restrict__ C0,
               int M, int N, int K, long sA, long sB, long sC)
{
    __shared__ bf16_t sAh[128 * 32];
    __shared__ bf16_t sBh[128 * 32];

    const int tid  = threadIdx.x;
    const int wave = tid >> 6;
    const int lane = tid & 63;
    const long bz  = blockIdx.z;

    const bf16_t* Ah = Ahi + bz * sA;
    const bf16_t* Bh = Bhi + bz * sB;

    const int row0 = blockIdx.y * 128;
    const int col0 = blockIdx.x * 128;
    const int wr = (wave >> 1) * 64;
    const int wc = (wave & 1) * 64;

    f32x4 acc[4][4] = {};

    const int ldrow = lane >> 2;
    const int ldcol = (lane & 3) * 8;
    const int hgrp  = (lane >> 4) * 8;
    const int fr    = lane & 15;

    for (int kt = 0; kt < K; kt += 32) {
        __syncthreads();
#pragma unroll
        for (int c = 0; c < 2; ++c) {
            const int chunk = wave * 2 + c;
            const int r = chunk * 16 + ldrow;
            GLOAD_LDS16(Ah + (long)(row0 + r) * K + kt + ldcol, &sAh[chunk * 512]);
            GLOAD_LDS16(Bh + (long)(col0 + r) * K + kt + ldcol, &sBh[chunk * 512]);
        }
        __syncthreads();

        bf16x8 aH[4], bH[4];
#pragma unroll
        for (int i = 0; i < 4; ++i)
            aH[i] = *(const bf16x8*)&sAh[(wr + i * 16 + fr) * 32 + hgrp];
#pragma unroll
        for (int j = 0; j < 4; ++j)
            bH[j] = *(const bf16x8*)&sBh[(wc + j * 16 + fr) * 32 + hgrp];
#pragma unroll
        for (int i = 0; i < 4; ++i)
#pragma unroll
            for (int j = 0; j < 4; ++j)
                acc[i][j] = MFMA16(aH[i], bH[j], acc[i][j]);
    }

    const int frow = (lane >> 4) * 4;
#pragma unroll
    for (int i = 0; i < 4; ++i) {
        const int rg = row0 + wr + i * 16 + frow;
#pragma unroll
        for (int j = 0; j < 4; ++j) {
            const int cg = col0 + wc + j * 16 + fr;
            if constexpr (EPI == 3) {
                float* C = (float*)C0 + bz * sC;
                const float badd = bias[cg];
#pragma unroll
                for (int r = 0; r < 4; ++r)
                    C[(long)(rg + r) * N + cg] = acc[i][j][r] + badd;
            } else {
                bf16_t* Ch = (bf16_t*)C0 + bz * sC;
#pragma unroll
                for (int r = 0; r < 4; ++r)
                    Ch[(long)(rg + r) * N + cg] = (bf16_t)acc[i][j][r];
            }
        }
    }
}

// ---------------------------------------------------------------------------
// Row softmax over length-1024 rows, in place (f32) + bf16 copy.
__global__ __launch_bounds__(256)
void softmax_rows(float* __restrict__ S, bf16_t* __restrict__ Sb)
{
    const long row = (long)blockIdx.x * 4 + (threadIdx.x >> 6);
    const int lane = threadIdx.x & 63;
    float* p = S + row * (long)TENC;

    float4 v[4];
    float m = -INFINITY;
#pragma unroll
    for (int i = 0; i < 4; ++i) {
        v[i] = *(const float4*)&p[i * 256 + lane * 4];
        m = fmaxf(fmaxf(fmaxf(v[i].x, v[i].y), fmaxf(v[i].z, v[i].w)), m);
    }
#pragma unroll
    for (int o = 32; o; o >>= 1) m = fmaxf(m, __shfl_xor(m, o, 64));

    float s = 0.f;
#pragma unroll
    for (int i = 0; i < 4; ++i) {
        v[i].x = __expf(v[i].x - m);
        v[i].y = __expf(v[i].y - m);
        v[i].z = __expf(v[i].z - m);
        v[i].w = __expf(v[i].w - m);
        s += v[i].x + v[i].y + v[i].z + v[i].w;
    }
#pragma unroll
    for (int o = 32; o; o >>= 1) s += __shfl_xor(s, o, 64);

    const float inv = 1.0f / s;
#pragma unroll
    for (int i = 0; i < 4; ++i) {
        v[i].x *= inv; v[i].y *= inv; v[i].z *= inv; v[i].w *= inv;
        *(float4*)&p[i * 256 + lane * 4] = v[i];
        if (Sb) {
            bf16x4 b;
            b[0] = (bf16_t)v[i].x; b[1] = (bf16_t)v[i].y;
            b[2] = (bf16_t)v[i].z; b[3] = (bf16_t)v[i].w;
            *(bf16x4*)&Sb[row * (long)TENC + i * 256 + lane * 4] = b;
        }
    }
}

// ---------------------------------------------------------------------------
// fp32 fallback GEMM (kept as ws-size safety net)
#define TILE_M 64
#define TILE_N 64
#define TILE_K 16
template<bool B_TRANS, bool ADD_BIAS>
__global__ __launch_bounds__(256)
void gemm_f32(const float* __restrict__ A, const float* __restrict__ Bm,
              const float* __restrict__ bias, float* __restrict__ C,
              int M, int N, int K, int lda, int ldb,
              long strideA, long strideB, long strideC)
{
    __shared__ float As[TILE_K][TILE_M + 4];
    __shared__ float Bs[TILE_K][TILE_N + 4];
    const int b = blockIdx.z;
    A += (long)b * strideA; Bm += (long)b * strideB; C += (long)b * strideC;
    const int tid = threadIdx.x;
    const int tx = tid & 15, ty = tid >> 4;
    const int row0 = blockIdx.y * TILE_M, col0 = blockIdx.x * TILE_N;
    const int am = tid >> 2, ak = (tid & 3) * 4;
    float acc[4][4] = {};
    for (int kt = 0; kt < K; kt += TILE_K) {
        float4 a4 = *(const float4*)&A[(long)(row0 + am) * lda + kt + ak];
        float4 b4;
        if (B_TRANS) b4 = *(const float4*)&Bm[(long)(col0 + am) * ldb + kt + ak];
        else {
            const int bk_ = tid >> 4, bn = (tid & 15) * 4;
            b4 = *(const float4*)&Bm[(long)(kt + bk_) * ldb + col0 + bn];
        }
        __syncthreads();
        As[ak + 0][am] = a4.x; As[ak + 1][am] = a4.y;
        As[ak + 2][am] = a4.z; As[ak + 3][am] = a4.w;
        if (B_TRANS) {
            Bs[ak + 0][am] = b4.x; Bs[ak + 1][am] = b4.y;
            Bs[ak + 2][am] = b4.z; Bs[ak + 3][am] = b4.w;
        } else {
            const int bk_ = tid >> 4, bn = (tid & 15) * 4;
            *(float4*)&Bs[bk_][bn] = b4;
        }
        __syncthreads();
#pragma unroll
        for (int k = 0; k < TILE_K; ++k) {
            float4 av = *(const float4*)&As[k][ty * 4];
            float4 bv4 = *(const float4*)&Bs[k][tx * 4];
            float ar[4] = {av.x, av.y, av.z, av.w};
            float br[4] = {bv4.x, bv4.y, bv4.z, bv4.w};
#pragma unroll
            for (int i = 0; i < 4; ++i)
#pragma unroll
                for (int j = 0; j < 4; ++j)
                    acc[i][j] = fmaf(ar[i], br[j], acc[i][j]);
        }
    }
    float4 bias4 = make_float4(0.f, 0.f, 0.f, 0.f);
    if (ADD_BIAS) bias4 = *(const float4*)&bias[col0 + tx * 4];
#pragma unroll
    for (int i = 0; i < 4; ++i) {
        float4 o;
        o.x = acc[i][0] + bias4.x; o.y = acc[i][1] + bias4.y;
        o.z = acc[i][2] + bias4.z; o.w = acc[i][3] + bias4.w;
        *(float4*)&C[(long)(row0 + ty * 4 + i) * N + col0 + tx * 4] = o;
    }
}

// ---------------------------------------------------------------------------
extern "C" void kernel_launch(void* const* d_in, const int* in_sizes, int n_in,
                              void* d_out, int out_size, void* d_ws, size_t ws_size,
                              hipStream_t stream)
{
    const float* enc = (const float*)d_in[0];
    const float* dec = (const float*)d_in[1];
    const float* Wk  = (const float*)d_in[2];
    const float* Wv  = (const float*)d_in[4];
    const float* bv  = (const float*)d_in[5];

    const long nE = (long)BB * TENC * DDIM;   // 16777216
    const long nD = (long)BB * TDEC * NST;    // 8388608
    const long nW = (long)DDIM * NST;         // 262144

    float* ctx   = (float*)d_out;             // [32,512,512]
    float* attnF = ctx + nD;                  // [32,512,1024]

    const size_t need = 85458944;
    const dim3 blk(256);

    if (ws_size < need) {
        float* ws = (float*)d_ws;
        gemm_f32<true, false><<<dim3(DDIM / 64, (BB * TDEC) / 64, 1), blk, 0, stream>>>(
            dec, Wk, nullptr, ws, BB * TDEC, DDIM, NST, NST, NST, 0, 0, 0);
        gemm_f32<true, false><<<dim3(TENC / 64, TDEC / 64, BB), blk, 0, stream>>>(
            ws, enc, nullptr, attnF, TDEC, TENC, DDIM, DDIM, DDIM,
            (long)TDEC * DDIM, (long)TENC * DDIM, (long)TDEC * TENC);
        softmax_rows<<<(BB * TDEC) / 4, blk, 0, stream>>>(attnF, nullptr);
        gemm_f32<false, false><<<dim3(DDIM / 64, TDEC / 64, BB), blk, 0, stream>>>(
            attnF, enc, nullptr, ws, TDEC, DDIM, TENC, TENC, DDIM,
            (long)TDEC * TENC, (long)TENC * DDIM, (long)TDEC * DDIM);
        gemm_f32<false, true><<<dim3(NST / 64, (BB * TDEC) / 64, 1), blk, 0, stream>>>(
            ws, Wv, bv, ctx, BB * TDEC, NST, DDIM, DDIM, NST, 0, 0, 0);
        return;
    }

    // ws layout (bytes)
    char* w = (char*)d_ws;
    bf16_t* Ehi  = (bf16_t*)(w);                 // later aliased: attn bf16
    bf16_t* Elo  = (bf16_t*)(w + 33554432);      // later aliased: enc^T bf16
    bf16_t* AE   = (bf16_t*)(w + 67108864);
    bf16_t* Wkhi = (bf16_t*)(w + 83886080);
    bf16_t* Wklo = (bf16_t*)(w + 84410368);
    bf16_t* WvT  = (bf16_t*)(w + 84934656);

    // scratch inside d_out (free until the owning GEMM writes it)
    bf16_t* Dhi   = (bf16_t*)attnF;              // dec hi/lo in attn region
    bf16_t* Dlo   = Dhi + nD;
    bf16_t* DKhi  = (bf16_t*)ctx;                // DK hi/lo in ctx region
    bf16_t* DKlo  = DKhi + nD;
    bf16_t* attnB = Ehi;
    bf16_t* ET    = Elo;

    // 1) conversions
    split_f32_bf16<<<(unsigned)((nD / 4 + 255) / 256), blk, 0, stream>>>(dec, Dhi, Dlo, nD / 4);
    split_f32_bf16<<<(unsigned)((nW / 4 + 255) / 256), blk, 0, stream>>>(Wk, Wkhi, Wklo, nW / 4);
    split_f32_bf16<<<(unsigned)((nE / 4 + 255) / 256), blk, 0, stream>>>(enc, Ehi, Elo, nE / 4);
    transpose_to_bf16<float><<<dim3(8, 8, 1), blk, 0, stream>>>(
        Wv, WvT, DDIM, NST, 0, 0);

    // 2) DK = dec @ Wk^T   (split x split, 2-barrier counted) -> split bf16 into ctx region
    gemm_split8<1><<<dim3(DDIM / 256, (BB * TDEC) / 128, 1), dim3(512), 0, stream>>>(
        Dhi, Dlo, Wkhi, Wklo, DKhi, DKlo,
        BB * TDEC, DDIM, NST, 0, 0, 0);

    // 3) score = DK @ enc^T  (split x split, 2-barrier counted) -> f32 attn region
    gemm_split8<0><<<dim3(TENC / 256, TDEC / 128, BB), dim3(512), 0, stream>>>(
        DKhi, DKlo, Ehi, Elo, attnF, nullptr,
        TDEC, TENC, DDIM,
        (long)TDEC * DDIM, (long)TENC * DDIM, (long)TDEC * TENC);

    // 4) enc^T bf16 (overwrites Elo — dead after score GEMM)
    transpose_to_bf16<bf16_t><<<dim3(DDIM / 64, TENC / 64, BB), blk, 0, stream>>>(
        Ehi, ET, TENC, DDIM, (long)TENC * DDIM, (long)DDIM * TENC);

    // 5) softmax (f32 in place; bf16 copy overwrites Ehi — dead)
    softmax_rows<<<(BB * TDEC) / 4, blk, 0, stream>>>(attnF, attnB);

    // 6) AE = attn @ enc  (plain bf16) -> bf16 ws
    mfma_gemm<2><<<dim3(DDIM / 128, TDEC / 128, BB), blk, 0, stream>>>(
        attnB, ET, nullptr, AE,
        TDEC, DDIM, TENC,
        (long)TDEC * TENC, (long)DDIM * TENC, (long)TDEC * DDIM);

    // 7) ctx = AE @ Wv^T' + bv  (plain bf16) -> f32 ctx
    mfma_gemm<3><<<dim3(NST / 128, (BB * TDEC) / 128, 1), blk, 0, stream>>>(
        AE, WvT, bv, ctx,
        BB * TDEC, NST, DDIM, 0, 0, 0);
}